// Round 3
// baseline (2638.447 us; speedup 1.0000x reference)
//
#include <hip/hip_runtime.h>
#include <math.h>

typedef __attribute__((ext_vector_type(8))) short short8;
typedef __attribute__((ext_vector_type(4))) float floatx4;
typedef unsigned short u16;

#define DEVFN static __device__ __forceinline__

DEVFN float b2f(u16 u) { union { unsigned int i; float f; } x; x.i = ((unsigned int)u) << 16; return x.f; }
DEVFN u16 f2b(float f) {
    union { float f; unsigned int i; } x; x.f = f;
    unsigned int r = (x.i + 0x7fffu + ((x.i >> 16) & 1u)) >> 16;
    return (u16)r;
}

DEVFN floatx4 mfma_bf16(short8 a, short8 b, floatx4 c) {
    return __builtin_amdgcn_mfma_f32_16x16x32_bf16(a, b, c, 0, 0, 0);
}

// ---------------- dtype detect: head_mask == 1.0 exactly.  bf16 word0 = 0x3F803F80, fp32 = 0x3F800000
__global__ void detect_k(const unsigned int* __restrict__ hm, int* __restrict__ flag) {
    if (threadIdx.x == 0) *flag = ((hm[0] & 0xFFFFu) != 0u) ? 1 : 0;  // 1 = inputs are bf16
}

// ---------------- canonicalize input -> bf16 buffer ----------------
__global__ void conv_k(const void* __restrict__ src, u16* __restrict__ dst, int n,
                       const int* __restrict__ flag) {
    int i = blockIdx.x * 256 + threadIdx.x;
    if (i < n) dst[i] = (*flag) ? ((const u16*)src)[i] : f2b(((const float*)src)[i]);
}

// ---------------- GEMM: C = A[M,K] @ B[K,N] + bias (all canonical bf16) ----------------
// MODE 0: QKV store: out bf16 at ((b*16+h)*1024+s)*64+d   (row=b*1024+s, col=h*64+d)
// MODE 1: out bf16 [M,N] = x + resid(bf16)[M,N]
// MODE 2: out bf16 [M,N] = gelu_exact(x)
template <int MODE>
__global__ __launch_bounds__(256, 2) void gemm_k(
    const u16* __restrict__ A, const u16* __restrict__ B,
    const u16* __restrict__ bias, const u16* __restrict__ resid,
    u16* __restrict__ Cout, int M, int N, int K) {
    __shared__ __align__(16) u16 As[128 * 40];
    __shared__ __align__(16) u16 Bs[128 * 40];
    const int m0 = blockIdx.x * 128, n0 = blockIdx.y * 128;
    const int tid = threadIdx.x;
    const int wave = tid >> 6, lane = tid & 63;
    const int wm = (wave >> 1) * 64, wn = (wave & 1) * 64;
    const int c = lane & 15, quad = lane >> 4;
    floatx4 acc[4][4] = {};
    for (int k0 = 0; k0 < K; k0 += 32) {
        __syncthreads();
        {   // A tile
            int ch = tid, row = ch >> 2, kc = ch & 3;
            *(uint4*)&As[row * 40 + kc * 8] = *(const uint4*)&A[(size_t)(m0 + row) * K + k0 + kc * 8];
            ch = tid + 256; row = ch >> 2; kc = ch & 3;
            *(uint4*)&As[row * 40 + kc * 8] = *(const uint4*)&A[(size_t)(m0 + row) * K + k0 + kc * 8];
        }
        {   // B tile: W[k0..k0+32, n0..n0+128] -> Bs[n][k] (transpose in LDS)
            int ch = tid, kr = ch >> 4, ng = (ch & 15) * 8;
            u16 tmp[8];
            *(uint4*)tmp = *(const uint4*)&B[(size_t)(k0 + kr) * N + n0 + ng];
#pragma unroll
            for (int j = 0; j < 8; j++) Bs[(ng + j) * 40 + kr] = tmp[j];
            ch = tid + 256; kr = ch >> 4; ng = (ch & 15) * 8;
            *(uint4*)tmp = *(const uint4*)&B[(size_t)(k0 + kr) * N + n0 + ng];
#pragma unroll
            for (int j = 0; j < 8; j++) Bs[(ng + j) * 40 + kr] = tmp[j];
        }
        __syncthreads();
        short8 af[4], bf[4];
#pragma unroll
        for (int mi = 0; mi < 4; mi++) af[mi] = *(const short8*)&As[(wm + mi * 16 + c) * 40 + quad * 8];
#pragma unroll
        for (int ni = 0; ni < 4; ni++) bf[ni] = *(const short8*)&Bs[(wn + ni * 16 + c) * 40 + quad * 8];
#pragma unroll
        for (int mi = 0; mi < 4; mi++)
#pragma unroll
            for (int ni = 0; ni < 4; ni++)
                acc[mi][ni] = mfma_bf16(af[mi], bf[ni], acc[mi][ni]);
    }
#pragma unroll
    for (int ni = 0; ni < 4; ni++) {
        int col = n0 + wn + ni * 16 + c;
        float bv = b2f(bias[col]);
#pragma unroll
        for (int mi = 0; mi < 4; mi++) {
#pragma unroll
            for (int r = 0; r < 4; r++) {
                int row = m0 + wm + mi * 16 + quad * 4 + r;
                float x = acc[mi][ni][r] + bv;
                size_t idx = (size_t)row * N + col;
                if (MODE == 0) {
                    int bb = row >> 10, s = row & 1023, h = col >> 6, d = col & 63;
                    Cout[((size_t)(bb * 16 + h) * 1024 + s) * 64 + d] = f2b(x);
                } else if (MODE == 1) {
                    Cout[idx] = f2b(x + b2f(resid[idx]));
                } else {
                    float gl = 0.5f * x * (1.0f + erff(x * 0.70710678118654752f));
                    Cout[idx] = f2b(gl);
                }
            }
        }
    }
}

// ---------------- flash attention with relative_key_query bias (all canonical bf16) ----------------
__global__ __launch_bounds__(256, 2) void attn_k(
    const u16* __restrict__ q, const u16* __restrict__ k, const u16* __restrict__ v,
    const u16* __restrict__ de, const u16* __restrict__ amask, const u16* __restrict__ hmask,
    u16* __restrict__ ctx) {
    __shared__ __align__(16) u16 U1[128 * 72];   // de band | { P [64][72], VT [64][72] @+4608 }
    __shared__ __align__(16) u16 Ks[64 * 72];
    __shared__ __align__(16) u16 QD[64 * 136];
    __shared__ __align__(16) u16 KD[64 * 136];
    const int bh = blockIdx.y, b = bh >> 4, h = bh & 15;
    const int L0 = blockIdx.x * 64;
    const int tid = threadIdx.x, wave = tid >> 6, lane = tid & 63;
    const int c = lane & 15, quad = lane >> 4;

    const size_t qrow = ((size_t)bh * 1024 + L0 + wave * 16 + c) * 64;
    const short8 qf0 = *(const short8*)&q[qrow + quad * 8];
    const short8 qf1 = *(const short8*)&q[qrow + 32 + quad * 8];

    floatx4 O[4] = {};
    float mrow[4] = {-1e30f, -1e30f, -1e30f, -1e30f};
    float lrow[4] = {0.f, 0.f, 0.f, 0.f};
    const float hm = b2f(hmask[h]);

    for (int rt = 0; rt < 16; rt++) {
        const int R0 = rt * 64;
        const int t0 = L0 - R0 + 960;
        __syncthreads();
        {
            int ch = tid, row = ch >> 3, kc = ch & 7;
            *(uint4*)&Ks[row * 72 + kc * 8] = *(const uint4*)&k[((size_t)bh * 1024 + R0 + row) * 64 + kc * 8];
            ch = tid + 256; row = ch >> 3; kc = ch & 7;
            *(uint4*)&Ks[row * 72 + kc * 8] = *(const uint4*)&k[((size_t)bh * 1024 + R0 + row) * 64 + kc * 8];
        }
#pragma unroll
        for (int i = 0; i < 4; i++) {
            int ch = tid + i * 256, row = ch >> 3, kc = ch & 7;
            int tr = t0 + row; if (tr > 2046) tr = 2046;
            *(uint4*)&U1[row * 72 + kc * 8] = *(const uint4*)&de[(size_t)tr * 64 + kc * 8];
        }
        __syncthreads();
#pragma unroll
        for (int ut = 0; ut < 8; ut++) {
            floatx4 a = {};
            a = mfma_bf16(qf0, *(const short8*)&U1[(ut * 16 + c) * 72 + quad * 8], a);
            a = mfma_bf16(qf1, *(const short8*)&U1[(ut * 16 + c) * 72 + 32 + quad * 8], a);
#pragma unroll
            for (int r = 0; r < 4; r++)
                QD[(wave * 16 + quad * 4 + r) * 136 + ut * 16 + c] = f2b(a[r]);
        }
        {
            short8 ka0 = *(const short8*)&Ks[(wave * 16 + c) * 72 + quad * 8];
            short8 ka1 = *(const short8*)&Ks[(wave * 16 + c) * 72 + 32 + quad * 8];
#pragma unroll
            for (int ut = 0; ut < 8; ut++) {
                floatx4 a = {};
                a = mfma_bf16(ka0, *(const short8*)&U1[(ut * 16 + c) * 72 + quad * 8], a);
                a = mfma_bf16(ka1, *(const short8*)&U1[(ut * 16 + c) * 72 + 32 + quad * 8], a);
#pragma unroll
                for (int r = 0; r < 4; r++)
                    KD[(wave * 16 + quad * 4 + r) * 136 + ut * 16 + c] = f2b(a[r]);
            }
        }
        __syncthreads();
        float sv[4][4];
#pragma unroll
        for (int nt = 0; nt < 4; nt++) {
            floatx4 a = {};
            a = mfma_bf16(qf0, *(const short8*)&Ks[(nt * 16 + c) * 72 + quad * 8], a);
            a = mfma_bf16(qf1, *(const short8*)&Ks[(nt * 16 + c) * 72 + 32 + quad * 8], a);
            int ri = nt * 16 + c;
            float am = b2f(amask[b * 1024 + R0 + ri]);
#pragma unroll
            for (int r = 0; r < 4; r++) {
                int li = wave * 16 + quad * 4 + r;
                int u = li - ri + 63;
                float biasv = b2f(QD[li * 136 + u]) + b2f(KD[ri * 136 + u]);
                sv[nt][r] = (a[r] + biasv) * 0.125f + am;
            }
        }
#pragma unroll
        for (int r = 0; r < 4; r++) {
            float rmax = fmaxf(fmaxf(sv[0][r], sv[1][r]), fmaxf(sv[2][r], sv[3][r]));
#pragma unroll
            for (int m = 1; m < 16; m <<= 1) rmax = fmaxf(rmax, __shfl_xor(rmax, m, 64));
            float mnew = fmaxf(mrow[r], rmax);
            float alpha = __expf(mrow[r] - mnew);
            float ps = 0.f;
#pragma unroll
            for (int nt = 0; nt < 4; nt++) { float p = __expf(sv[nt][r] - mnew); sv[nt][r] = p; ps += p; }
#pragma unroll
            for (int m = 1; m < 16; m <<= 1) ps += __shfl_xor(ps, m, 64);
            lrow[r] = lrow[r] * alpha + ps;
            mrow[r] = mnew;
            O[0][r] *= alpha; O[1][r] *= alpha; O[2][r] *= alpha; O[3][r] *= alpha;
        }
#pragma unroll
        for (int nt = 0; nt < 4; nt++)
#pragma unroll
            for (int r = 0; r < 4; r++)
                U1[(wave * 16 + quad * 4 + r) * 72 + nt * 16 + c] = f2b(sv[nt][r]);
        __syncthreads();
        {
            int ch = tid, row = ch >> 3, kc = ch & 7;
            uint4 raw = *(const uint4*)&v[((size_t)bh * 1024 + R0 + row) * 64 + kc * 8];
            u16 tmpv[8]; *(uint4*)tmpv = raw;
#pragma unroll
            for (int j = 0; j < 8; j++) U1[4608 + (kc * 8 + j) * 72 + row] = tmpv[j];
            ch = tid + 256; row = ch >> 3; kc = ch & 7;
            raw = *(const uint4*)&v[((size_t)bh * 1024 + R0 + row) * 64 + kc * 8];
            *(uint4*)tmpv = raw;
#pragma unroll
            for (int j = 0; j < 8; j++) U1[4608 + (kc * 8 + j) * 72 + row] = tmpv[j];
        }
        __syncthreads();
        {
            short8 pa0 = *(const short8*)&U1[(wave * 16 + c) * 72 + quad * 8];
            short8 pa1 = *(const short8*)&U1[(wave * 16 + c) * 72 + 32 + quad * 8];
#pragma unroll
            for (int dt = 0; dt < 4; dt++) {
                O[dt] = mfma_bf16(pa0, *(const short8*)&U1[4608 + (dt * 16 + c) * 72 + quad * 8], O[dt]);
                O[dt] = mfma_bf16(pa1, *(const short8*)&U1[4608 + (dt * 16 + c) * 72 + 32 + quad * 8], O[dt]);
            }
        }
    }
#pragma unroll
    for (int r = 0; r < 4; r++) {
        float inv = hm / lrow[r];
        int s = L0 + wave * 16 + quad * 4 + r;
#pragma unroll
        for (int dt = 0; dt < 4; dt++)
            ctx[(((size_t)b * 1024 + s) * 16 + h) * 64 + dt * 16 + c] = f2b(O[dt][r] * inv);
    }
}

// ---------------- LayerNorm over 1024 bf16 -> bf16 (FINAL: d_out, dtype per flag) ----------------
template <int FINAL>
__global__ __launch_bounds__(256) void ln_k(const u16* __restrict__ x, const u16* __restrict__ g,
                                            const u16* __restrict__ bb, void* __restrict__ out,
                                            const int* __restrict__ flag) {
    const int row = blockIdx.x, tid = threadIdx.x;
    const u16* xr = x + (size_t)row * 1024;
    float vv[4];
#pragma unroll
    for (int j = 0; j < 4; j++) vv[j] = b2f(xr[tid * 4 + j]);
    float s = vv[0] + vv[1] + vv[2] + vv[3];
    float ss = vv[0] * vv[0] + vv[1] * vv[1] + vv[2] * vv[2] + vv[3] * vv[3];
#pragma unroll
    for (int m = 1; m < 64; m <<= 1) { s += __shfl_xor(s, m, 64); ss += __shfl_xor(ss, m, 64); }
    __shared__ float red[8];
    int wave = tid >> 6, lane = tid & 63;
    if (lane == 0) { red[wave] = s; red[wave + 4] = ss; }
    __syncthreads();
    s = red[0] + red[1] + red[2] + red[3];
    ss = red[4] + red[5] + red[6] + red[7];
    float mu = s * (1.f / 1024.f);
    float var = ss * (1.f / 1024.f) - mu * mu;
    float rs = rsqrtf(var + 1e-12f);
    const int out_bf16 = FINAL ? *flag : 1;
#pragma unroll
    for (int j = 0; j < 4; j++) {
        int idx = tid * 4 + j;
        float val = (vv[j] - mu) * rs * b2f(g[idx]) + b2f(bb[idx]);
        if (out_bf16) ((u16*)out)[(size_t)row * 1024 + idx] = f2b(val);
        else          ((float*)out)[(size_t)row * 1024 + idx] = val;
    }
}

extern "C" void kernel_launch(void* const* d_in, const int* in_sizes, int n_in,
                              void* d_out, int out_size, void* d_ws, size_t ws_size,
                              hipStream_t stream) {
    (void)in_sizes; (void)n_in; (void)out_size; (void)ws_size;
    const void* hidden = d_in[0];
    const void* amaskI = d_in[1];
    const void* hmaskI = d_in[2];
    const void* Wq = d_in[3];  const void* bq = d_in[4];
    const void* Wk = d_in[5];  const void* bk = d_in[6];
    const void* Wv = d_in[7];  const void* bv = d_in[8];
    const void* de = d_in[9];
    const void* Wo = d_in[10]; const void* bo = d_in[11];
    const void* ln1g = d_in[12]; const void* ln1b = d_in[13];
    const void* Wi = d_in[14]; const void* bi = d_in[15];
    const void* Wo2 = d_in[16]; const void* bo2 = d_in[17];
    const void* ln2g = d_in[18]; const void* ln2b = d_in[19];

    // ---- workspace layout (49 MiB total), lifetime-overlapped ----
    //  [ 0, 8M): Q (P1-attn)        -> cWo2 (FF strips)
    //  [ 8,16M): K (P1-attn)        -> preLN bf16 (LN1 in, LN2 in)
    //  [16,24M): V (P1-attn)        -> AttnOut (LN1 out .. FF2 resid)
    //  [24,32M): Ctx (attn-WoGEMM)  -> cWi (FF strips)
    //  [32,40M): cHidden (P0-WoGEMM)-> InterStrip 4M (FF strips)
    //  [40,48M): cWq|cWk|cWv|cWo
    //  [48M..):  cDe (0.5M) | smalls (35KB) | flag
    const size_t MB = 1048576;
    char* ws = (char*)d_ws;
    u16* wsQ    = (u16*)(ws);
    u16* wsK    = (u16*)(ws + 8 * MB);
    u16* wsV    = (u16*)(ws + 16 * MB);
    u16* wsCtx  = (u16*)(ws + 24 * MB);
    u16* cHid   = (u16*)(ws + 32 * MB);
    u16* cWq    = (u16*)(ws + 40 * MB);
    u16* cWk    = (u16*)(ws + 42 * MB);
    u16* cWv    = (u16*)(ws + 44 * MB);
    u16* cWo    = (u16*)(ws + 46 * MB);
    u16* cDe    = (u16*)(ws + 48 * MB);
    u16* smalls = (u16*)(ws + 48 * MB + 524288);
    int* flag   = (int*)(ws + 49 * MB - 256);
    // overlapped late-phase views
    u16* cWo2  = wsQ;
    u16* preLN = wsK;
    u16* attnO = wsV;
    u16* cWi   = wsCtx;
    u16* strip = cHid;   // 512x4096 bf16 = 4 MB

    u16* s_bq = smalls, *s_bk = smalls + 1024, *s_bv = smalls + 2048, *s_bo = smalls + 3072;
    u16* s_bi = smalls + 4096, *s_bo2 = smalls + 8192;
    u16* s_l1g = smalls + 9216, *s_l1b = smalls + 10240, *s_l2g = smalls + 11264, *s_l2b = smalls + 12288;
    u16* s_am = smalls + 13312, *s_hm = smalls + 17408;

    detect_k<<<1, 64, 0, stream>>>((const unsigned int*)hmaskI, flag);

    auto conv = [&](const void* src, u16* dst, int n) {
        conv_k<<<(n + 255) / 256, 256, 0, stream>>>(src, dst, n, flag);
    };
    conv(hidden, cHid, 4194304);
    conv(Wq, cWq, 1048576);
    conv(Wk, cWk, 1048576);
    conv(Wv, cWv, 1048576);
    conv(Wo, cWo, 1048576);
    conv(de, cDe, 2047 * 64);
    conv(bq, s_bq, 1024); conv(bk, s_bk, 1024); conv(bv, s_bv, 1024); conv(bo, s_bo, 1024);
    conv(bi, s_bi, 4096); conv(bo2, s_bo2, 1024);
    conv(ln1g, s_l1g, 1024); conv(ln1b, s_l1b, 1024);
    conv(ln2g, s_l2g, 1024); conv(ln2b, s_l2b, 1024);
    conv(amaskI, s_am, 4096); conv(hmaskI, s_hm, 16);

    // QKV projections -> [B,H,S,D]
    gemm_k<0><<<dim3(32, 8), 256, 0, stream>>>(cHid, cWq, s_bq, nullptr, wsQ, 4096, 1024, 1024);
    gemm_k<0><<<dim3(32, 8), 256, 0, stream>>>(cHid, cWk, s_bk, nullptr, wsK, 4096, 1024, 1024);
    gemm_k<0><<<dim3(32, 8), 256, 0, stream>>>(cHid, cWv, s_bv, nullptr, wsV, 4096, 1024, 1024);

    // attention -> ctx [B,S,H,D]
    attn_k<<<dim3(16, 64), 256, 0, stream>>>(wsQ, wsK, wsV, cDe, s_am, s_hm, wsCtx);

    // ctx @ Wo + bo + hidden -> preLN (bf16, overwrites K region)
    gemm_k<1><<<dim3(32, 8), 256, 0, stream>>>(wsCtx, cWo, s_bo, cHid, preLN, 4096, 1024, 1024);

    // convert FF weights into now-dead regions (Q -> Wo2, Ctx -> Wi)
    conv(Wi, cWi, 4194304);
    conv(Wo2, cWo2, 4194304);

    // LN1 -> AttnOut (overwrites V region)
    ln_k<0><<<4096, 256, 0, stream>>>(preLN, s_l1g, s_l1b, attnO, flag);

    // FF in 8 row-strips of 512 (Inter never materialized beyond 4 MB)
    for (int s = 0; s < 8; s++) {
        const u16* aoff = attnO + (size_t)s * 512 * 1024;
        gemm_k<2><<<dim3(4, 32), 256, 0, stream>>>(aoff, cWi, s_bi, nullptr, strip, 512, 4096, 1024);
        gemm_k<1><<<dim3(4, 8), 256, 0, stream>>>(strip, cWo2, s_bo2, aoff,
                                                  preLN + (size_t)s * 512 * 1024, 512, 1024, 4096);
    }

    // LN2 -> d_out (dtype per flag)
    ln_k<1><<<4096, 256, 0, stream>>>(preLN, s_l2g, s_l2b, d_out, flag);
}

// Round 4
// 612.763 us; speedup vs baseline: 4.3058x; 4.3058x over previous
//
#include <hip/hip_runtime.h>
#include <math.h>

typedef __attribute__((ext_vector_type(8))) short short8;
typedef __attribute__((ext_vector_type(4))) float floatx4;
typedef unsigned short u16;

#define DEVFN static __device__ __forceinline__

DEVFN float b2f(u16 u) { union { unsigned int i; float f; } x; x.i = ((unsigned int)u) << 16; return x.f; }
DEVFN u16 f2b(float f) {
    union { float f; unsigned int i; } x; x.f = f;
    unsigned int r = (x.i + 0x7fffu + ((x.i >> 16) & 1u)) >> 16;
    return (u16)r;
}

DEVFN floatx4 mfma_bf16(short8 a, short8 b, floatx4 c) {
    return __builtin_amdgcn_mfma_f32_16x16x32_bf16(a, b, c, 0, 0, 0);
}

// ---------------- dtype detect: head_mask == 1.0 exactly.  bf16 word0 = 0x3F803F80, fp32 = 0x3F800000
__global__ void detect_k(const unsigned int* __restrict__ hm, int* __restrict__ flag) {
    if (threadIdx.x == 0) *flag = ((hm[0] & 0xFFFFu) != 0u) ? 1 : 0;  // 1 = inputs are bf16
}

// ---------------- canonicalize input -> bf16 buffer ----------------
__global__ void conv_k(const void* __restrict__ src, u16* __restrict__ dst, int n,
                       const int* __restrict__ flag) {
    int i = blockIdx.x * 256 + threadIdx.x;
    if (i < n) dst[i] = (*flag) ? ((const u16*)src)[i] : f2b(((const float*)src)[i]);
}

// ---------------- fused convert + transpose: src [R,C] -> dst bf16 [C,R] ----------------
__global__ void convT_k(const void* __restrict__ src, u16* __restrict__ dst, int R, int C,
                        const int* __restrict__ flag) {
    __shared__ u16 t[32][33];
    int bx = blockIdx.x * 32, by = blockIdx.y * 32;
    int tx = threadIdx.x, ty = threadIdx.y;  // 32 x 8
    if (*flag) {
        const u16* s = (const u16*)src;
        for (int j = ty; j < 32; j += 8) t[j][tx] = s[(size_t)(by + j) * C + bx + tx];
    } else {
        const float* s = (const float*)src;
        for (int j = ty; j < 32; j += 8) t[j][tx] = f2b(s[(size_t)(by + j) * C + bx + tx]);
    }
    __syncthreads();
    for (int j = ty; j < 32; j += 8) dst[(size_t)(bx + j) * R + by + tx] = t[tx][j];
}

// ---------------- GEMM: C = A[M,K] @ Bt[N,K]^T + bias (canonical bf16) ----------------
// MODE 0: QKV concat store (N=3072): col -> which=col>>10 (q/k/v), h, d; out[which*4M + ((b*16+h)*1024+s)*64+d]
// MODE 1: out bf16 [M,N] = x + resid(bf16)[M,N]
// MODE 2: out bf16 [M,N] = gelu_exact(x)
template <int MODE>
__global__ __launch_bounds__(256, 2) void gemm_k(
    const u16* __restrict__ A, const u16* __restrict__ Bt,
    const u16* __restrict__ bias, const u16* __restrict__ resid,
    u16* __restrict__ Cout, int M, int N, int K) {
    __shared__ __align__(16) u16 As[128 * 40];
    __shared__ __align__(16) u16 Bs[128 * 40];
    const int m0 = blockIdx.x * 128, n0 = blockIdx.y * 128;
    const int tid = threadIdx.x;
    const int wave = tid >> 6, lane = tid & 63;
    const int wm = (wave >> 1) * 64, wn = (wave & 1) * 64;
    const int c = lane & 15, quad = lane >> 4;
    floatx4 acc[4][4] = {};
    for (int k0 = 0; k0 < K; k0 += 32) {
        __syncthreads();
        {
            int ch = tid, row = ch >> 2, kc = ch & 3;
            *(uint4*)&As[row * 40 + kc * 8] = *(const uint4*)&A[(size_t)(m0 + row) * K + k0 + kc * 8];
            *(uint4*)&Bs[row * 40 + kc * 8] = *(const uint4*)&Bt[(size_t)(n0 + row) * K + k0 + kc * 8];
            ch = tid + 256; row = ch >> 2; kc = ch & 3;
            *(uint4*)&As[row * 40 + kc * 8] = *(const uint4*)&A[(size_t)(m0 + row) * K + k0 + kc * 8];
            *(uint4*)&Bs[row * 40 + kc * 8] = *(const uint4*)&Bt[(size_t)(n0 + row) * K + k0 + kc * 8];
        }
        __syncthreads();
        short8 af[4], bf[4];
#pragma unroll
        for (int mi = 0; mi < 4; mi++) af[mi] = *(const short8*)&As[(wm + mi * 16 + c) * 40 + quad * 8];
#pragma unroll
        for (int ni = 0; ni < 4; ni++) bf[ni] = *(const short8*)&Bs[(wn + ni * 16 + c) * 40 + quad * 8];
#pragma unroll
        for (int mi = 0; mi < 4; mi++)
#pragma unroll
            for (int ni = 0; ni < 4; ni++)
                acc[mi][ni] = mfma_bf16(af[mi], bf[ni], acc[mi][ni]);
    }
#pragma unroll
    for (int ni = 0; ni < 4; ni++) {
        int col = n0 + wn + ni * 16 + c;
        float bv = b2f(bias[col]);
#pragma unroll
        for (int mi = 0; mi < 4; mi++) {
#pragma unroll
            for (int r = 0; r < 4; r++) {
                int row = m0 + wm + mi * 16 + quad * 4 + r;
                float x = acc[mi][ni][r] + bv;
                size_t idx = (size_t)row * N + col;
                if (MODE == 0) {
                    int which = col >> 10, rem = col & 1023, h = rem >> 6, d = rem & 63;
                    int bb = row >> 10, s = row & 1023;
                    Cout[(size_t)which * 4194304 + ((size_t)(bb * 16 + h) * 1024 + s) * 64 + d] = f2b(x);
                } else if (MODE == 1) {
                    Cout[idx] = f2b(x + b2f(resid[idx]));
                } else {
                    float gl = 0.5f * x * (1.0f + erff(x * 0.70710678118654752f));
                    Cout[idx] = f2b(gl);
                }
            }
        }
    }
}

// ---------------- flash attention with relative_key_query bias (canonical bf16) ----------------
__global__ __launch_bounds__(256, 2) void attn_k(
    const u16* __restrict__ q, const u16* __restrict__ k, const u16* __restrict__ v,
    const u16* __restrict__ de, const u16* __restrict__ amask, const u16* __restrict__ hmask,
    u16* __restrict__ ctx) {
    __shared__ __align__(16) u16 U1[128 * 72];   // de band | { P [64][72], VT [64][72] @+4608 }
    __shared__ __align__(16) u16 Ks[64 * 72];
    __shared__ __align__(16) u16 QD[64 * 136];
    __shared__ __align__(16) u16 KD[64 * 136];
    const int bh = blockIdx.y, b = bh >> 4, h = bh & 15;
    const int L0 = blockIdx.x * 64;
    const int tid = threadIdx.x, wave = tid >> 6, lane = tid & 63;
    const int c = lane & 15, quad = lane >> 4;

    const size_t qrow = ((size_t)bh * 1024 + L0 + wave * 16 + c) * 64;
    const short8 qf0 = *(const short8*)&q[qrow + quad * 8];
    const short8 qf1 = *(const short8*)&q[qrow + 32 + quad * 8];

    floatx4 O[4] = {};
    float mrow[4] = {-1e30f, -1e30f, -1e30f, -1e30f};
    float lrow[4] = {0.f, 0.f, 0.f, 0.f};
    const float hm = b2f(hmask[h]);

    for (int rt = 0; rt < 16; rt++) {
        const int R0 = rt * 64;
        const int t0 = L0 - R0 + 960;
        __syncthreads();
        {
            int ch = tid, row = ch >> 3, kc = ch & 7;
            *(uint4*)&Ks[row * 72 + kc * 8] = *(const uint4*)&k[((size_t)bh * 1024 + R0 + row) * 64 + kc * 8];
            ch = tid + 256; row = ch >> 3; kc = ch & 7;
            *(uint4*)&Ks[row * 72 + kc * 8] = *(const uint4*)&k[((size_t)bh * 1024 + R0 + row) * 64 + kc * 8];
        }
#pragma unroll
        for (int i = 0; i < 4; i++) {
            int ch = tid + i * 256, row = ch >> 3, kc = ch & 7;
            int tr = t0 + row; if (tr > 2046) tr = 2046;
            *(uint4*)&U1[row * 72 + kc * 8] = *(const uint4*)&de[(size_t)tr * 64 + kc * 8];
        }
        __syncthreads();
#pragma unroll
        for (int ut = 0; ut < 8; ut++) {
            floatx4 a = {};
            a = mfma_bf16(qf0, *(const short8*)&U1[(ut * 16 + c) * 72 + quad * 8], a);
            a = mfma_bf16(qf1, *(const short8*)&U1[(ut * 16 + c) * 72 + 32 + quad * 8], a);
#pragma unroll
            for (int r = 0; r < 4; r++)
                QD[(wave * 16 + quad * 4 + r) * 136 + ut * 16 + c] = f2b(a[r]);
        }
        {
            short8 ka0 = *(const short8*)&Ks[(wave * 16 + c) * 72 + quad * 8];
            short8 ka1 = *(const short8*)&Ks[(wave * 16 + c) * 72 + 32 + quad * 8];
#pragma unroll
            for (int ut = 0; ut < 8; ut++) {
                floatx4 a = {};
                a = mfma_bf16(ka0, *(const short8*)&U1[(ut * 16 + c) * 72 + quad * 8], a);
                a = mfma_bf16(ka1, *(const short8*)&U1[(ut * 16 + c) * 72 + 32 + quad * 8], a);
#pragma unroll
                for (int r = 0; r < 4; r++)
                    KD[(wave * 16 + quad * 4 + r) * 136 + ut * 16 + c] = f2b(a[r]);
            }
        }
        __syncthreads();
        float sv[4][4];
#pragma unroll
        for (int nt = 0; nt < 4; nt++) {
            floatx4 a = {};
            a = mfma_bf16(qf0, *(const short8*)&Ks[(nt * 16 + c) * 72 + quad * 8], a);
            a = mfma_bf16(qf1, *(const short8*)&Ks[(nt * 16 + c) * 72 + 32 + quad * 8], a);
            int ri = nt * 16 + c;
            float am = b2f(amask[b * 1024 + R0 + ri]);
#pragma unroll
            for (int r = 0; r < 4; r++) {
                int li = wave * 16 + quad * 4 + r;
                int u = li - ri + 63;
                float biasv = b2f(QD[li * 136 + u]) + b2f(KD[ri * 136 + u]);
                sv[nt][r] = (a[r] + biasv) * 0.125f + am;
            }
        }
#pragma unroll
        for (int r = 0; r < 4; r++) {
            float rmax = fmaxf(fmaxf(sv[0][r], sv[1][r]), fmaxf(sv[2][r], sv[3][r]));
#pragma unroll
            for (int m = 1; m < 16; m <<= 1) rmax = fmaxf(rmax, __shfl_xor(rmax, m, 64));
            float mnew = fmaxf(mrow[r], rmax);
            float alpha = __expf(mrow[r] - mnew);
            float ps = 0.f;
#pragma unroll
            for (int nt = 0; nt < 4; nt++) { float p = __expf(sv[nt][r] - mnew); sv[nt][r] = p; ps += p; }
#pragma unroll
            for (int m = 1; m < 16; m <<= 1) ps += __shfl_xor(ps, m, 64);
            lrow[r] = lrow[r] * alpha + ps;
            mrow[r] = mnew;
            O[0][r] *= alpha; O[1][r] *= alpha; O[2][r] *= alpha; O[3][r] *= alpha;
        }
#pragma unroll
        for (int nt = 0; nt < 4; nt++)
#pragma unroll
            for (int r = 0; r < 4; r++)
                U1[(wave * 16 + quad * 4 + r) * 72 + nt * 16 + c] = f2b(sv[nt][r]);
        __syncthreads();
        {
            int ch = tid, row = ch >> 3, kc = ch & 7;
            uint4 raw = *(const uint4*)&v[((size_t)bh * 1024 + R0 + row) * 64 + kc * 8];
            u16 tmpv[8]; *(uint4*)tmpv = raw;
#pragma unroll
            for (int j = 0; j < 8; j++) U1[4608 + (kc * 8 + j) * 72 + row] = tmpv[j];
            ch = tid + 256; row = ch >> 3; kc = ch & 7;
            raw = *(const uint4*)&v[((size_t)bh * 1024 + R0 + row) * 64 + kc * 8];
            *(uint4*)tmpv = raw;
#pragma unroll
            for (int j = 0; j < 8; j++) U1[4608 + (kc * 8 + j) * 72 + row] = tmpv[j];
        }
        __syncthreads();
        {
            short8 pa0 = *(const short8*)&U1[(wave * 16 + c) * 72 + quad * 8];
            short8 pa1 = *(const short8*)&U1[(wave * 16 + c) * 72 + 32 + quad * 8];
#pragma unroll
            for (int dt = 0; dt < 4; dt++) {
                O[dt] = mfma_bf16(pa0, *(const short8*)&U1[4608 + (dt * 16 + c) * 72 + quad * 8], O[dt]);
                O[dt] = mfma_bf16(pa1, *(const short8*)&U1[4608 + (dt * 16 + c) * 72 + 32 + quad * 8], O[dt]);
            }
        }
    }
#pragma unroll
    for (int r = 0; r < 4; r++) {
        float inv = hm / lrow[r];
        int s = L0 + wave * 16 + quad * 4 + r;
#pragma unroll
        for (int dt = 0; dt < 4; dt++)
            ctx[(((size_t)b * 1024 + s) * 16 + h) * 64 + dt * 16 + c] = f2b(O[dt][r] * inv);
    }
}

// ---------------- LayerNorm over 1024 bf16 -> bf16 (FINAL: d_out, dtype per flag) ----------------
template <int FINAL>
__global__ __launch_bounds__(256) void ln_k(const u16* __restrict__ x, const u16* __restrict__ g,
                                            const u16* __restrict__ bb, void* __restrict__ out,
                                            const int* __restrict__ flag) {
    const int row = blockIdx.x, tid = threadIdx.x;
    const u16* xr = x + (size_t)row * 1024;
    float vv[4];
#pragma unroll
    for (int j = 0; j < 4; j++) vv[j] = b2f(xr[tid * 4 + j]);
    float s = vv[0] + vv[1] + vv[2] + vv[3];
    float ss = vv[0] * vv[0] + vv[1] * vv[1] + vv[2] * vv[2] + vv[3] * vv[3];
#pragma unroll
    for (int m = 1; m < 64; m <<= 1) { s += __shfl_xor(s, m, 64); ss += __shfl_xor(ss, m, 64); }
    __shared__ float red[8];
    int wave = tid >> 6, lane = tid & 63;
    if (lane == 0) { red[wave] = s; red[wave + 4] = ss; }
    __syncthreads();
    s = red[0] + red[1] + red[2] + red[3];
    ss = red[4] + red[5] + red[6] + red[7];
    float mu = s * (1.f / 1024.f);
    float var = ss * (1.f / 1024.f) - mu * mu;
    float rs = rsqrtf(var + 1e-12f);
    const int out_bf16 = FINAL ? *flag : 1;
#pragma unroll
    for (int j = 0; j < 4; j++) {
        int idx = tid * 4 + j;
        float val = (vv[j] - mu) * rs * b2f(g[idx]) + b2f(bb[idx]);
        if (out_bf16) ((u16*)out)[(size_t)row * 1024 + idx] = f2b(val);
        else          ((float*)out)[(size_t)row * 1024 + idx] = val;
    }
}

extern "C" void kernel_launch(void* const* d_in, const int* in_sizes, int n_in,
                              void* d_out, int out_size, void* d_ws, size_t ws_size,
                              hipStream_t stream) {
    (void)in_sizes; (void)n_in; (void)out_size;
    const void* hidden = d_in[0];
    const void* amaskI = d_in[1];
    const void* hmaskI = d_in[2];
    const void* Wq = d_in[3];  const void* bq = d_in[4];
    const void* Wk = d_in[5];  const void* bk = d_in[6];
    const void* Wv = d_in[7];  const void* bv = d_in[8];
    const void* de = d_in[9];
    const void* Wo = d_in[10]; const void* bo = d_in[11];
    const void* ln1g = d_in[12]; const void* ln1b = d_in[13];
    const void* Wi = d_in[14]; const void* bi = d_in[15];
    const void* Wo2 = d_in[16]; const void* bo2 = d_in[17];
    const void* ln2g = d_in[18]; const void* ln2b = d_in[19];

    const size_t MB = 1048576;
    char* ws = (char*)d_ws;
    const bool big = (ws_size >= (size_t)70 * MB);

    // ---- layouts (lifetime-overlapped) ----
    // FULL (>=70MB): R0[0,32M)=Q|K|V|Ctx -> Inter ; R1[32,40M)=cHid -> cWo2T ;
    //                R2[40,48M)=preLN ; R3[48,56M)=attnO ;
    //                R4[56,64M)=cQKVT(6M)+cWoT(2M) -> cWiT(8M) ; cDe@64M ; smalls ; flag
    // SMALL (<70MB): R0[0,32M)=Q|K|V|Ctx ; later Inter-strip@[0,16M), preLN@[16,24M), attnO@[24,32M)
    //                cHid@[32,40M)->cWo2T ; cQKVT@[40,46M)+cWoT@[46,48M) -> cWiT@[40,48M) ;
    //                cDe@48M ; smalls ; flag   (peak ~49MB, as validated in round 3)
    u16* wsQKV  = (u16*)(ws);                      // Q@0, K@+4M elts, V@+8M elts
    u16* wsCtx  = (u16*)(ws + 24 * MB);
    u16* wsInter= (u16*)(ws);                      // full path: 32MB over QKV+Ctx
    u16* cHid   = (u16*)(ws + 32 * MB);
    u16* cWo2T  = (u16*)(ws + 32 * MB);            // after cHid dead
    u16* preLN  = big ? (u16*)(ws + 40 * MB) : (u16*)(ws + 16 * MB);
    u16* attnO  = big ? (u16*)(ws + 48 * MB) : (u16*)(ws + 24 * MB);
    u16* cQKVT  = big ? (u16*)(ws + 56 * MB) : (u16*)(ws + 40 * MB);
    u16* cWoT   = big ? (u16*)(ws + 62 * MB) : (u16*)(ws + 46 * MB);
    u16* cWiT   = cQKVT;                           // 8MB over cQKVT+cWoT after both dead
    u16* cDe    = big ? (u16*)(ws + 64 * MB) : (u16*)(ws + 48 * MB);
    u16* smalls = (u16*)((char*)cDe + 262144);
    int* flag   = (int*)((char*)smalls + 65536);

    u16* s_bqkv = smalls;                 // 3072
    u16* s_bo   = smalls + 3072;          // 1024
    u16* s_bi   = smalls + 4096;          // 4096
    u16* s_bo2  = smalls + 8192;          // 1024
    u16* s_l1g  = smalls + 9216, *s_l1b = smalls + 10240;
    u16* s_l2g  = smalls + 11264, *s_l2b = smalls + 12288;
    u16* s_am   = smalls + 13312;         // 4096
    u16* s_hm   = smalls + 17408;         // 16

    detect_k<<<1, 64, 0, stream>>>((const unsigned int*)hmaskI, flag);

    auto conv = [&](const void* src, u16* dst, int n) {
        conv_k<<<(n + 255) / 256, 256, 0, stream>>>(src, dst, n, flag);
    };
    auto convT = [&](const void* src, u16* dst, int R, int C) {
        convT_k<<<dim3(C / 32, R / 32), dim3(32, 8), 0, stream>>>(src, dst, R, C, flag);
    };

    conv(hidden, cHid, 4194304);
    convT(Wq, cQKVT, 1024, 1024);
    convT(Wk, cQKVT + 1048576, 1024, 1024);
    convT(Wv, cQKVT + 2097152, 1024, 1024);
    convT(Wo, cWoT, 1024, 1024);
    conv(de, cDe, 2047 * 64);
    conv(bq, s_bqkv, 1024); conv(bk, s_bqkv + 1024, 1024); conv(bv, s_bqkv + 2048, 1024);
    conv(bo, s_bo, 1024);
    conv(bi, s_bi, 4096); conv(bo2, s_bo2, 1024);
    conv(ln1g, s_l1g, 1024); conv(ln1b, s_l1b, 1024);
    conv(ln2g, s_l2g, 1024); conv(ln2b, s_l2b, 1024);
    conv(amaskI, s_am, 4096); conv(hmaskI, s_hm, 16);

    // fused QKV projection -> Q|K|V [B,H,S,D] each
    gemm_k<0><<<dim3(32, 24), 256, 0, stream>>>(cHid, cQKVT, s_bqkv, nullptr, wsQKV, 4096, 3072, 1024);

    // attention -> ctx [B,S,H,D]
    attn_k<<<dim3(16, 64), 256, 0, stream>>>(wsQKV, wsQKV + 4194304, wsQKV + 8388608,
                                             cDe, s_am, s_hm, wsCtx);

    // ctx @ Wo + bo + hidden -> preLN
    gemm_k<1><<<dim3(32, 8), 256, 0, stream>>>(wsCtx, cWoT, s_bo, cHid, preLN, 4096, 1024, 1024);

    // FF weights into now-dead regions
    convT(Wi, cWiT, 1024, 4096);    // WiT [4096,1024]
    convT(Wo2, cWo2T, 4096, 1024);  // Wo2T [1024,4096]

    // LN1 -> attnO
    ln_k<0><<<4096, 256, 0, stream>>>(preLN, s_l1g, s_l1b, attnO, flag);

    if (big) {
        gemm_k<2><<<dim3(32, 32), 256, 0, stream>>>(attnO, cWiT, s_bi, nullptr, wsInter, 4096, 4096, 1024);
        gemm_k<1><<<dim3(32, 8), 256, 0, stream>>>(wsInter, cWo2T, s_bo2, attnO, preLN, 4096, 1024, 4096);
    } else {
        u16* strip = (u16*)(ws);  // 2048x4096 bf16 = 16MB over dead Q|K
        for (int s = 0; s < 2; s++) {
            const u16* aoff = attnO + (size_t)s * 2048 * 1024;
            gemm_k<2><<<dim3(16, 32), 256, 0, stream>>>(aoff, cWiT, s_bi, nullptr, strip, 2048, 4096, 1024);
            gemm_k<1><<<dim3(16, 8), 256, 0, stream>>>(strip, cWo2T, s_bo2, aoff,
                                                       preLN + (size_t)s * 2048 * 1024, 2048, 1024, 4096);
        }
    }

    // LN2 -> d_out (dtype per flag)
    ln_k<1><<<4096, 256, 0, stream>>>(preLN, s_l2g, s_l2b, d_out, flag);
}